// Round 1
// baseline (1908.947 us; speedup 1.0000x reference)
//
#include <hip/hip_runtime.h>
#include <math.h>

#define BB 4
#define NN 8192
#define PP 32768
#define KNN 16

// ---------------- embed1: h1 = pts @ w1 + b1  [P,64] ----------------
__global__ __launch_bounds__(256) void k_embed1(const float* __restrict__ pts,
    const float* __restrict__ w1, const float* __restrict__ b1, float* __restrict__ h1)
{
  int tid = threadIdx.x;
  int c = tid & 63, g = tid >> 6;
  float wx = w1[c], wy = w1[64 + c], wz = w1[128 + c], bc = b1[c];
  int base = blockIdx.x * 256;
  #pragma unroll 4
  for (int i = 0; i < 64; ++i) {
    int p = base + g + i * 4;
    float px = pts[p*3+0], py = pts[p*3+1], pz = pts[p*3+2];
    float h = fmaf(pz, wz, fmaf(py, wy, fmaf(px, wx, bc)));
    h1[(size_t)p*64 + c] = h;
  }
}

// ---------------- generic per-channel sum/sumsq over P points ----------------
template<int C>
__global__ __launch_bounds__(256) void k_stats(const float* __restrict__ src,
    float* __restrict__ gsum, float* __restrict__ gss)
{
  constexpr int GPB = 256 / C;  // point-groups per block
  int tid = threadIdx.x;
  int c = tid % C, g = tid / C;
  float s = 0.f, ss = 0.f;
  for (int p = blockIdx.x * GPB + g; p < PP; p += gridDim.x * GPB) {
    float v = src[(size_t)p*C + c];
    s += v; ss = fmaf(v, v, ss);
  }
  __shared__ float ls[256], lq[256];
  ls[tid] = s; lq[tid] = ss;
  __syncthreads();
  if (tid < C) {
    float a = 0.f, b2 = 0.f;
    #pragma unroll
    for (int i = 0; i < GPB; ++i) { a += ls[tid + i*C]; b2 += lq[tid + i*C]; }
    atomicAdd(gsum + tid, a);
    atomicAdd(gss + tid, b2);
  }
}

// ---------------- finalize BN: scale = g/sqrt(var+eps), shift = b - mean*scale ----------------
__global__ void k_finalize(int C, const float* __restrict__ gsum, const float* __restrict__ gss,
    const float* __restrict__ gg, const float* __restrict__ bb,
    float* __restrict__ sc, float* __restrict__ sh)
{
  int c = threadIdx.x;
  if (c >= C) return;
  float mean = gsum[c] * (1.0f / PP);
  float var  = gss[c] * (1.0f / PP) - mean * mean;
  float s = gg[c] / sqrtf(var + 1e-5f);
  sc[c] = s;
  sh[c] = bb[c] - mean * s;
}

// ---------------- generic projection: out = relu(bn(in)) @ W (+bias) ----------------
// blockIdx.y selects one of up to 3 (W, bias, out) triples (lin/src/dst share input x).
template<int K, int COUT>
__global__ __launch_bounds__(256) void k_proj(const float* __restrict__ in,
    const float* __restrict__ sc, const float* __restrict__ sh,
    const float* __restrict__ W0, const float* __restrict__ W1, const float* __restrict__ W2,
    const float* __restrict__ B0, const float* __restrict__ B1, const float* __restrict__ B2,
    float* __restrict__ O0, float* __restrict__ O1, float* __restrict__ O2)
{
  constexpr int PTS = 64;
  constexpr int CW = 8;
  constexpr int CG = COUT / CW;        // channel groups: 8 (COUT=64) or 16 (COUT=128)
  constexpr int PW = PTS * CG / 256;   // points per thread: 2 or 4
  const float* W  = (blockIdx.y == 0) ? W0 : (blockIdx.y == 1) ? W1 : W2;
  const float* Bb = (blockIdx.y == 0) ? B0 : (blockIdx.y == 1) ? B1 : B2;
  float*       O  = (blockIdx.y == 0) ? O0 : (blockIdx.y == 1) ? O1 : O2;
  __shared__ float xs[PTS][K + 1];
  int tid = threadIdx.x;
  int pbase = blockIdx.x * PTS;
  constexpr int T4 = PTS * K / 4;
  for (int i = tid; i < T4; i += 256) {
    int p = i / (K/4), k = (i % (K/4)) * 4;
    float4 v = *(const float4*)(in + (size_t)(pbase + p)*K + k);
    v.x = fmaxf(fmaf(v.x, sc[k+0], sh[k+0]), 0.f);
    v.y = fmaxf(fmaf(v.y, sc[k+1], sh[k+1]), 0.f);
    v.z = fmaxf(fmaf(v.z, sc[k+2], sh[k+2]), 0.f);
    v.w = fmaxf(fmaf(v.w, sc[k+3], sh[k+3]), 0.f);
    xs[p][k+0] = v.x; xs[p][k+1] = v.y; xs[p][k+2] = v.z; xs[p][k+3] = v.w;
  }
  __syncthreads();
  int cg = tid % CG, pg = tid / CG;
  int c0 = cg * CW, p0 = pg * PW;
  float acc[PW][CW];
  #pragma unroll
  for (int i = 0; i < PW; ++i) {
    #pragma unroll
    for (int j = 0; j < CW; ++j) acc[i][j] = 0.f;
  }
  #pragma unroll 4
  for (int k = 0; k < K; ++k) {
    float4 wa = *(const float4*)(W + (size_t)k*COUT + c0);
    float4 wb = *(const float4*)(W + (size_t)k*COUT + c0 + 4);
    #pragma unroll
    for (int i = 0; i < PW; ++i) {
      float x = xs[p0 + i][k];
      acc[i][0] = fmaf(x, wa.x, acc[i][0]);
      acc[i][1] = fmaf(x, wa.y, acc[i][1]);
      acc[i][2] = fmaf(x, wa.z, acc[i][2]);
      acc[i][3] = fmaf(x, wa.w, acc[i][3]);
      acc[i][4] = fmaf(x, wb.x, acc[i][4]);
      acc[i][5] = fmaf(x, wb.y, acc[i][5]);
      acc[i][6] = fmaf(x, wb.z, acc[i][6]);
      acc[i][7] = fmaf(x, wb.w, acc[i][7]);
    }
  }
  float bj[CW];
  #pragma unroll
  for (int j = 0; j < CW; ++j) bj[j] = Bb ? Bb[c0 + j] : 0.f;
  #pragma unroll
  for (int i = 0; i < PW; ++i) {
    float* op = O + (size_t)(pbase + p0 + i)*COUT + c0;
    *(float4*)(op)     = make_float4(acc[i][0]+bj[0], acc[i][1]+bj[1], acc[i][2]+bj[2], acc[i][3]+bj[3]);
    *(float4*)(op + 4) = make_float4(acc[i][4]+bj[4], acc[i][5]+bj[5], acc[i][6]+bj[6], acc[i][7]+bj[7]);
  }
}

// ---------------- kNN-16 per batch (self excluded), rounding-matched to reference ----------------
// 2 threads per query: each scans 4096 candidates keeping a sorted top-16, then LDS merge.
__global__ __launch_bounds__(256) void k_knn(const float* __restrict__ pts, int* __restrict__ idxout)
{
  int tid = threadIdx.x;
  int b = blockIdx.y;
  int ql = tid & 127, half = tid >> 7;
  int q = blockIdx.x * 128 + ql;
  const float* pb = pts + (size_t)b * NN * 3;
  float qx = pb[q*3+0], qy = pb[q*3+1], qz = pb[q*3+2];
  float qs = __fadd_rn(__fadd_rn(__fmul_rn(qx,qx), __fmul_rn(qy,qy)), __fmul_rn(qz,qz));
  float d2v[16]; int idv[16];
  #pragma unroll
  for (int k = 0; k < 16; ++k) { d2v[k] = 3.4e38f; idv[k] = -1; }
  __shared__ float4 tile[2][128];
  for (int it = 0; it < 32; ++it) {
    __syncthreads();
    {
      int hh = tid >> 7, cc = tid & 127;
      int jj = hh * 4096 + it * 128 + cc;
      float x = pb[jj*3+0], y = pb[jj*3+1], z = pb[jj*3+2];
      float sq = __fadd_rn(__fadd_rn(__fmul_rn(x,x), __fmul_rn(y,y)), __fmul_rn(z,z));
      tile[hh][cc] = make_float4(x, y, z, sq);
    }
    __syncthreads();
    int jbase = half * 4096 + it * 128;
    #pragma unroll 2
    for (int t = 0; t < 128; ++t) {
      float4 cn = tile[half][t];
      float dot = __fadd_rn(__fadd_rn(__fmul_rn(qx,cn.x), __fmul_rn(qy,cn.y)), __fmul_rn(qz,cn.z));
      float d2  = __fsub_rn(__fadd_rn(qs, cn.w), __fmul_rn(2.0f, dot));
      int j = jbase + t;
      if (d2 < d2v[0] && j != q) {         // strict < : ties keep earlier (smaller) index, matching top_k
        d2v[0] = d2; idv[0] = j;
        #pragma unroll
        for (int k = 0; k < 15; ++k) {     // one bubble pass restores descending order
          if (d2v[k] < d2v[k+1]) {
            float td = d2v[k]; d2v[k] = d2v[k+1]; d2v[k+1] = td;
            int   ti = idv[k]; idv[k] = idv[k+1]; idv[k+1] = ti;
          }
        }
      }
    }
  }
  __shared__ float md[256][16];
  __shared__ int   mi[256][16];
  #pragma unroll
  for (int k = 0; k < 16; ++k) { md[tid][k] = d2v[15-k]; mi[tid][k] = idv[15-k]; } // ascending
  __syncthreads();
  if (tid < 128) {
    int ia = 0, ib = 0;
    size_t ob = ((size_t)b * NN + q) * KNN;
    #pragma unroll
    for (int n = 0; n < 16; ++n) {
      float da = md[tid][ia], db = md[tid+128][ib];
      int   ja = mi[tid][ia], jb = mi[tid+128][ib];
      bool ta = (da < db) || (da == db && ja < jb);
      idxout[ob + n] = ta ? ja : jb;
      if (ta) ++ia; else ++ib;
    }
  }
}

// ---------------- PointTransformerConv: one wave per point, 2 channels per lane ----------------
__global__ __launch_bounds__(256) void k_conv(const float* __restrict__ V, const float* __restrict__ S,
    const float* __restrict__ D, const float* __restrict__ pts, const int* __restrict__ idx,
    const float* __restrict__ pw, const float* __restrict__ pbv, float* __restrict__ Y)
{
  int lane = threadIdx.x & 63;
  int wid  = (blockIdx.x * 256 + threadIdx.x) >> 6;  // 4096 waves
  int c0 = lane * 2;
  float2 w0  = *(const float2*)(pw + c0);
  float2 w1  = *(const float2*)(pw + 128 + c0);
  float2 w2  = *(const float2*)(pw + 256 + c0);
  float2 pb2 = *(const float2*)(pbv + c0);
  for (int p = wid; p < PP; p += 4096) {
    int b = p >> 13, self = p & (NN - 1);
    const float* pbase = pts + (size_t)b * NN * 3;
    float pix = pbase[self*3+0], piy = pbase[self*3+1], piz = pbase[self*3+2];
    float2 di = *(const float2*)(D + (size_t)p*128 + c0);
    float m0 = -3.4e38f, m1 = -3.4e38f, l0 = 0.f, l1 = 0.f, a0 = 0.f, a1 = 0.f;
    for (int t = 0; t < 17; ++t) {         // 16 kNN + self loop (appended last, as in reference)
      int j = (t < 16) ? idx[p*KNN + t] : self;
      float dx = pix - pbase[j*3+0];
      float dy = piy - pbase[j*3+1];
      float dz = piz - pbase[j*3+2];
      size_t off = ((size_t)b * NN + j) * 128 + c0;
      float2 sj = *(const float2*)(S + off);
      float2 vj = *(const float2*)(V + off);
      float de0 = fmaf(dz, w2.x, fmaf(dy, w1.x, fmaf(dx, w0.x, pb2.x)));
      float de1 = fmaf(dz, w2.y, fmaf(dy, w1.y, fmaf(dx, w0.y, pb2.y)));
      float g0 = di.x - sj.x + de0;
      float g1 = di.y - sj.y + de1;
      float mn0 = fmaxf(m0, g0), mn1 = fmaxf(m1, g1);
      float cr0 = __expf(m0 - mn0), cr1 = __expf(m1 - mn1);
      float e0  = __expf(g0 - mn0), e1  = __expf(g1 - mn1);
      l0 = fmaf(l0, cr0, e0);
      l1 = fmaf(l1, cr1, e1);
      a0 = fmaf(a0, cr0, e0 * (vj.x + de0));
      a1 = fmaf(a1, cr1, e1 * (vj.y + de1));
      m0 = mn0; m1 = mn1;
    }
    float2 o; o.x = a0 / l0; o.y = a1 / l1;
    *(float2*)(Y + (size_t)p*128 + c0) = o;
  }
}

// ---------------- decoder head: logits = relu(bn(t)) @ dec_w2 + dec_b2 ----------------
__global__ __launch_bounds__(256) void k_dec2(const float* __restrict__ T,
    const float* __restrict__ sc, const float* __restrict__ sh,
    const float* __restrict__ W, const float* __restrict__ bias, float* __restrict__ out)
{
  __shared__ float xs[64][132];   // row stride 132 floats -> 16B-aligned float4 rows
  __shared__ float wt[13][128];
  int tid = threadIdx.x;
  int pb = blockIdx.x * 64;
  for (int i = tid; i < 13 * 128; i += 256) {
    int cls = i >> 7, k = i & 127;
    wt[cls][k] = W[k*13 + cls];
  }
  for (int i = tid; i < 64 * 32; i += 256) {
    int p = i >> 5, k = (i & 31) * 4;
    float4 v = *(const float4*)(T + (size_t)(pb + p)*128 + k);
    v.x = fmaxf(fmaf(v.x, sc[k+0], sh[k+0]), 0.f);
    v.y = fmaxf(fmaf(v.y, sc[k+1], sh[k+1]), 0.f);
    v.z = fmaxf(fmaf(v.z, sc[k+2], sh[k+2]), 0.f);
    v.w = fmaxf(fmaf(v.w, sc[k+3], sh[k+3]), 0.f);
    xs[p][k+0] = v.x; xs[p][k+1] = v.y; xs[p][k+2] = v.z; xs[p][k+3] = v.w;
  }
  __syncthreads();
  for (int o = tid; o < 64 * 13; o += 256) {
    int p = o / 13, cls = o - p * 13;
    float acc = bias[cls];
    const float4* xr = (const float4*)&xs[p][0];
    const float4* wr = (const float4*)&wt[cls][0];
    #pragma unroll 8
    for (int k4 = 0; k4 < 32; ++k4) {
      float4 a = xr[k4], w = wr[k4];
      acc = fmaf(a.x, w.x, acc);
      acc = fmaf(a.y, w.y, acc);
      acc = fmaf(a.z, w.z, acc);
      acc = fmaf(a.w, w.w, acc);
    }
    out[(size_t)(pb + p)*13 + cls] = acc;
  }
}

extern "C" void kernel_launch(void* const* d_in, const int* in_sizes, int n_in,
                              void* d_out, int out_size, void* d_ws, size_t ws_size,
                              hipStream_t stream)
{
  const float* pts      = (const float*)d_in[0];
  const float* embed_w1 = (const float*)d_in[1];
  const float* embed_b1 = (const float*)d_in[2];
  const float* bn1_g    = (const float*)d_in[3];
  const float* bn1_b    = (const float*)d_in[4];
  const float* embed_w2 = (const float*)d_in[5];
  const float* embed_b2 = (const float*)d_in[6];
  const float* bne_g    = (const float*)d_in[7];
  const float* bne_b    = (const float*)d_in[8];
  const float* l0_lin   = (const float*)d_in[9];
  const float* l0_src   = (const float*)d_in[10];
  const float* l0_dst   = (const float*)d_in[11];
  const float* l0_pos_w = (const float*)d_in[12];
  const float* l0_pos_b = (const float*)d_in[13];
  const float* l0_bn_g  = (const float*)d_in[14];
  const float* l0_bn_b  = (const float*)d_in[15];
  const float* l1_lin   = (const float*)d_in[16];
  const float* l1_src   = (const float*)d_in[17];
  const float* l1_dst   = (const float*)d_in[18];
  const float* l1_pos_w = (const float*)d_in[19];
  const float* l1_pos_b = (const float*)d_in[20];
  const float* l1_bn_g  = (const float*)d_in[21];
  const float* l1_bn_b  = (const float*)d_in[22];
  const float* dec_w1   = (const float*)d_in[23];
  const float* dec_b1   = (const float*)d_in[24];
  const float* dec_bn_g = (const float*)d_in[25];
  const float* dec_bn_b = (const float*)d_in[26];
  const float* dec_w2   = (const float*)d_in[27];
  const float* dec_b2   = (const float*)d_in[28];

  char* ws = (char*)d_ws;
  const size_t MB = 1024 * 1024;
  float* h1  = (float*)(ws + 0);          // 8 MB  [P,64]
  float* h2  = (float*)(ws + 8*MB);       // 8 MB  [P,64]
  int*   idx = (int*)  (ws + 16*MB);      // 2 MB  [P,16]
  float* v0  = (float*)(ws + 18*MB);      // 16 MB [P,128]  (reused for layer1)
  float* s0  = (float*)(ws + 34*MB);      // 16 MB
  float* d0  = (float*)(ws + 50*MB);      // 16 MB
  float* y0  = (float*)(ws + 66*MB);      // 16 MB
  float* y1  = (float*)(ws + 82*MB);      // 16 MB
  float* tt  = (float*)(ws + 0);          // 16 MB overlay on h1/h2 (dead by then)
  float* st  = (float*)(ws + 98*MB);      // 8 KB stats
  float *sum1=st+0,    *ss1=st+64,   *sc1=st+128,  *sh1=st+192;
  float *sum2=st+256,  *ss2=st+320,  *sc2=st+384,  *sh2=st+448;
  float *sum3=st+512,  *ss3=st+640,  *sc3=st+768,  *sh3=st+896;
  float *sum4=st+1024, *ss4=st+1152, *sc4=st+1280, *sh4=st+1408;
  float *sum5=st+1536, *ss5=st+1664, *sc5=st+1792, *sh5=st+1920;

  hipMemsetAsync(st, 0, 2048 * sizeof(float), stream);

  // embedding MLP
  k_embed1<<<128, 256, 0, stream>>>(pts, embed_w1, embed_b1, h1);
  k_stats<64><<<128, 256, 0, stream>>>(h1, sum1, ss1);
  k_finalize<<<1, 64, 0, stream>>>(64, sum1, ss1, bn1_g, bn1_b, sc1, sh1);
  k_proj<64,64><<<dim3(512,1), 256, 0, stream>>>(h1, sc1, sh1,
      embed_w2, embed_w2, embed_w2, embed_b2, embed_b2, embed_b2, h2, h2, h2);
  k_stats<64><<<128, 256, 0, stream>>>(h2, sum2, ss2);
  k_finalize<<<1, 64, 0, stream>>>(64, sum2, ss2, bne_g, bne_b, sc2, sh2);

  // kNN graph
  k_knn<<<dim3(64, 4), 256, 0, stream>>>(pts, idx);

  // layer 0
  k_proj<64,128><<<dim3(512,3), 256, 0, stream>>>(h2, sc2, sh2,
      l0_lin, l0_src, l0_dst, nullptr, nullptr, nullptr, v0, s0, d0);
  k_conv<<<1024, 256, 0, stream>>>(v0, s0, d0, pts, idx, l0_pos_w, l0_pos_b, y0);
  k_stats<128><<<128, 256, 0, stream>>>(y0, sum3, ss3);
  k_finalize<<<1, 128, 0, stream>>>(128, sum3, ss3, l0_bn_g, l0_bn_b, sc3, sh3);

  // layer 1
  k_proj<128,128><<<dim3(512,3), 256, 0, stream>>>(y0, sc3, sh3,
      l1_lin, l1_src, l1_dst, nullptr, nullptr, nullptr, v0, s0, d0);
  k_conv<<<1024, 256, 0, stream>>>(v0, s0, d0, pts, idx, l1_pos_w, l1_pos_b, y1);
  k_stats<128><<<128, 256, 0, stream>>>(y1, sum4, ss4);
  k_finalize<<<1, 128, 0, stream>>>(128, sum4, ss4, l1_bn_g, l1_bn_b, sc4, sh4);

  // decoder
  k_proj<128,128><<<dim3(512,1), 256, 0, stream>>>(y1, sc4, sh4,
      dec_w1, dec_w1, dec_w1, dec_b1, dec_b1, dec_b1, tt, tt, tt);
  k_stats<128><<<128, 256, 0, stream>>>(tt, sum5, ss5);
  k_finalize<<<1, 128, 0, stream>>>(128, sum5, ss5, dec_bn_g, dec_bn_b, sc5, sh5);
  k_dec2<<<512, 256, 0, stream>>>(tt, sc5, sh5, dec_w2, dec_b2, (float*)d_out);
}

// Round 2
// 781.360 us; speedup vs baseline: 2.4431x; 2.4431x over previous
//
#include <hip/hip_runtime.h>
#include <math.h>

#define BB 4
#define NN 8192
#define PP 32768
#define KNN 16

// ---------------- embed1: h1 = pts @ w1 + b1  [P,64] ----------------
__global__ __launch_bounds__(256) void k_embed1(const float* __restrict__ pts,
    const float* __restrict__ w1, const float* __restrict__ b1, float* __restrict__ h1)
{
  int tid = threadIdx.x;
  int c = tid & 63, g = tid >> 6;
  float wx = w1[c], wy = w1[64 + c], wz = w1[128 + c], bc = b1[c];
  int base = blockIdx.x * 256;
  #pragma unroll 4
  for (int i = 0; i < 64; ++i) {
    int p = base + g + i * 4;
    float px = pts[p*3+0], py = pts[p*3+1], pz = pts[p*3+2];
    float h = fmaf(pz, wz, fmaf(py, wy, fmaf(px, wx, bc)));
    h1[(size_t)p*64 + c] = h;
  }
}

// ---------------- prep for kNN: pts4[p] = (x,y,z,|p|^2) ----------------
__global__ __launch_bounds__(256) void k_prep(const float* __restrict__ pts, float4* __restrict__ pts4)
{
  int p = blockIdx.x * 256 + threadIdx.x;
  float x = pts[p*3+0], y = pts[p*3+1], z = pts[p*3+2];
  float sq = __fadd_rn(__fadd_rn(__fmul_rn(x,x), __fmul_rn(y,y)), __fmul_rn(z,z));
  pts4[p] = make_float4(x, y, z, sq);
}

// ---------------- generic per-channel sum/sumsq over P points ----------------
template<int C>
__global__ __launch_bounds__(256) void k_stats(const float* __restrict__ src,
    float* __restrict__ gsum, float* __restrict__ gss)
{
  constexpr int GPB = 256 / C;  // point-groups per block
  int tid = threadIdx.x;
  int c = tid % C, g = tid / C;
  float s = 0.f, ss = 0.f;
  for (int p = blockIdx.x * GPB + g; p < PP; p += gridDim.x * GPB) {
    float v = src[(size_t)p*C + c];
    s += v; ss = fmaf(v, v, ss);
  }
  __shared__ float ls[256], lq[256];
  ls[tid] = s; lq[tid] = ss;
  __syncthreads();
  if (tid < C) {
    float a = 0.f, b2 = 0.f;
    #pragma unroll
    for (int i = 0; i < GPB; ++i) { a += ls[tid + i*C]; b2 += lq[tid + i*C]; }
    atomicAdd(gsum + tid, a);
    atomicAdd(gss + tid, b2);
  }
}

// ---------------- finalize BN: scale = g/sqrt(var+eps), shift = b - mean*scale ----------------
__global__ void k_finalize(int C, const float* __restrict__ gsum, const float* __restrict__ gss,
    const float* __restrict__ gg, const float* __restrict__ bb,
    float* __restrict__ sc, float* __restrict__ sh)
{
  int c = threadIdx.x;
  if (c >= C) return;
  float mean = gsum[c] * (1.0f / PP);
  float var  = gss[c] * (1.0f / PP) - mean * mean;
  float s = gg[c] / sqrtf(var + 1e-5f);
  sc[c] = s;
  sh[c] = bb[c] - mean * s;
}

// ---------------- generic projection: out = relu(bn(in)) @ W (+bias) ----------------
// blockIdx.y selects one of up to 3 (W, bias, out) triples (lin/src/dst share input x).
template<int K, int COUT>
__global__ __launch_bounds__(256) void k_proj(const float* __restrict__ in,
    const float* __restrict__ sc, const float* __restrict__ sh,
    const float* __restrict__ W0, const float* __restrict__ W1, const float* __restrict__ W2,
    const float* __restrict__ B0, const float* __restrict__ B1, const float* __restrict__ B2,
    float* __restrict__ O0, float* __restrict__ O1, float* __restrict__ O2)
{
  constexpr int PTS = 64;
  constexpr int CW = 8;
  constexpr int CG = COUT / CW;        // channel groups: 8 (COUT=64) or 16 (COUT=128)
  constexpr int PW = PTS * CG / 256;   // points per thread: 2 or 4
  const float* W  = (blockIdx.y == 0) ? W0 : (blockIdx.y == 1) ? W1 : W2;
  const float* Bb = (blockIdx.y == 0) ? B0 : (blockIdx.y == 1) ? B1 : B2;
  float*       O  = (blockIdx.y == 0) ? O0 : (blockIdx.y == 1) ? O1 : O2;
  __shared__ float xs[PTS][K + 1];
  int tid = threadIdx.x;
  int pbase = blockIdx.x * PTS;
  constexpr int T4 = PTS * K / 4;
  for (int i = tid; i < T4; i += 256) {
    int p = i / (K/4), k = (i % (K/4)) * 4;
    float4 v = *(const float4*)(in + (size_t)(pbase + p)*K + k);
    v.x = fmaxf(fmaf(v.x, sc[k+0], sh[k+0]), 0.f);
    v.y = fmaxf(fmaf(v.y, sc[k+1], sh[k+1]), 0.f);
    v.z = fmaxf(fmaf(v.z, sc[k+2], sh[k+2]), 0.f);
    v.w = fmaxf(fmaf(v.w, sc[k+3], sh[k+3]), 0.f);
    xs[p][k+0] = v.x; xs[p][k+1] = v.y; xs[p][k+2] = v.z; xs[p][k+3] = v.w;
  }
  __syncthreads();
  int cg = tid % CG, pg = tid / CG;
  int c0 = cg * CW, p0 = pg * PW;
  float acc[PW][CW];
  #pragma unroll
  for (int i = 0; i < PW; ++i) {
    #pragma unroll
    for (int j = 0; j < CW; ++j) acc[i][j] = 0.f;
  }
  #pragma unroll 4
  for (int k = 0; k < K; ++k) {
    float4 wa = *(const float4*)(W + (size_t)k*COUT + c0);
    float4 wb = *(const float4*)(W + (size_t)k*COUT + c0 + 4);
    #pragma unroll
    for (int i = 0; i < PW; ++i) {
      float x = xs[p0 + i][k];
      acc[i][0] = fmaf(x, wa.x, acc[i][0]);
      acc[i][1] = fmaf(x, wa.y, acc[i][1]);
      acc[i][2] = fmaf(x, wa.z, acc[i][2]);
      acc[i][3] = fmaf(x, wa.w, acc[i][3]);
      acc[i][4] = fmaf(x, wb.x, acc[i][4]);
      acc[i][5] = fmaf(x, wb.y, acc[i][5]);
      acc[i][6] = fmaf(x, wb.z, acc[i][6]);
      acc[i][7] = fmaf(x, wb.w, acc[i][7]);
    }
  }
  float bj[CW];
  #pragma unroll
  for (int j = 0; j < CW; ++j) bj[j] = Bb ? Bb[c0 + j] : 0.f;
  #pragma unroll
  for (int i = 0; i < PW; ++i) {
    float* op = O + (size_t)(pbase + p0 + i)*COUT + c0;
    *(float4*)(op)     = make_float4(acc[i][0]+bj[0], acc[i][1]+bj[1], acc[i][2]+bj[2], acc[i][3]+bj[3]);
    *(float4*)(op + 4) = make_float4(acc[i][4]+bj[4], acc[i][5]+bj[5], acc[i][6]+bj[6], acc[i][7]+bj[7]);
  }
}

// ---------------- kNN-16: one wave per query, ballot-select + cross-lane sorted list ----------------
// Top-16 list lives across lanes: lane l (l&15) holds list[l&15], replicated x4 across the
// wave's four 16-lane groups. Per 64-candidate chunk: ballot(d2 < tau) selects candidates,
// which are serialized in increasing-j order (wave-uniform scalar loop) and inserted via a
// parallel shfl_up shift. tau = list[15] via v_readlane. Strict < keeps first-scanned on ties,
// matching jax.lax.top_k tie-breaking (smaller index first). d2 rounding matches reference:
// (sq_i + sq_j) - 2*dot with _rn ops, no FMA contraction.
__global__ __launch_bounds__(256) void k_knn(const float4* __restrict__ pts4, int* __restrict__ idxout)
{
  int lane = threadIdx.x & 63;
  int wv = (blockIdx.x * 256 + threadIdx.x) >> 6;   // global wave id = query id
  int b = wv >> 13, q = wv & (NN - 1);
  const float4* pb = pts4 + (size_t)b * NN;
  float4 qp = pb[q];
  float lval = 3.4e38f;   // list value held by this lane (ascending in l16)
  int   lidx = 0;
  float tau  = 3.4e38f;   // wave-uniform 16th-best
  int l16 = lane & 15;
  for (int c = 0; c < 128; ++c) {
    int j = c * 64 + lane;
    float4 cn = pb[j];
    float dot = __fadd_rn(__fadd_rn(__fmul_rn(qp.x,cn.x), __fmul_rn(qp.y,cn.y)), __fmul_rn(qp.z,cn.z));
    float d2  = __fsub_rn(__fadd_rn(qp.w, cn.w), __fmul_rn(2.0f, dot));
    if (j == q) d2 = 3.4e38f;                       // exclude self (ref adds 1e10 on diagonal)
    unsigned long long mask = __ballot(d2 < tau);
    while (mask) {
      int src = __ffsll((unsigned long long)mask) - 1;   // lowest lane first -> increasing j
      mask &= mask - 1;
      float v = __uint_as_float(__builtin_amdgcn_readlane(__float_as_uint(d2), src));
      if (v < tau) {                                // re-check against updated tau (uniform branch)
        int jc = c * 64 + src;
        float pv = __shfl_up(lval, 1, 16);
        int   pi = __shfl_up(lidx, 1, 16);
        bool atpos = (l16 == 0) || (pv <= v);
        if (lval > v) {
          lval = atpos ? v  : pv;
          lidx = atpos ? jc : pi;
        }
        tau = __uint_as_float(__builtin_amdgcn_readlane(__float_as_uint(lval), 15));
      }
    }
  }
  if (lane < 16) idxout[(size_t)wv * KNN + lane] = lidx;
}

// ---------------- PointTransformerConv: one wave per point, 2 channels per lane ----------------
__global__ __launch_bounds__(256) void k_conv(const float* __restrict__ V, const float* __restrict__ S,
    const float* __restrict__ D, const float* __restrict__ pts, const int* __restrict__ idx,
    const float* __restrict__ pw, const float* __restrict__ pbv, float* __restrict__ Y)
{
  int lane = threadIdx.x & 63;
  int wid  = (blockIdx.x * 256 + threadIdx.x) >> 6;  // 4096 waves
  int c0 = lane * 2;
  float2 w0  = *(const float2*)(pw + c0);
  float2 w1  = *(const float2*)(pw + 128 + c0);
  float2 w2  = *(const float2*)(pw + 256 + c0);
  float2 pb2 = *(const float2*)(pbv + c0);
  for (int p = wid; p < PP; p += 4096) {
    int b = p >> 13, self = p & (NN - 1);
    const float* pbase = pts + (size_t)b * NN * 3;
    float pix = pbase[self*3+0], piy = pbase[self*3+1], piz = pbase[self*3+2];
    float2 di = *(const float2*)(D + (size_t)p*128 + c0);
    float m0 = -3.4e38f, m1 = -3.4e38f, l0 = 0.f, l1 = 0.f, a0 = 0.f, a1 = 0.f;
    for (int t = 0; t < 17; ++t) {         // 16 kNN + self loop (appended last, as in reference)
      int j = (t < 16) ? idx[p*KNN + t] : self;
      float dx = pix - pbase[j*3+0];
      float dy = piy - pbase[j*3+1];
      float dz = piz - pbase[j*3+2];
      size_t off = ((size_t)b * NN + j) * 128 + c0;
      float2 sj = *(const float2*)(S + off);
      float2 vj = *(const float2*)(V + off);
      float de0 = fmaf(dz, w2.x, fmaf(dy, w1.x, fmaf(dx, w0.x, pb2.x)));
      float de1 = fmaf(dz, w2.y, fmaf(dy, w1.y, fmaf(dx, w0.y, pb2.y)));
      float g0 = di.x - sj.x + de0;
      float g1 = di.y - sj.y + de1;
      float mn0 = fmaxf(m0, g0), mn1 = fmaxf(m1, g1);
      float cr0 = __expf(m0 - mn0), cr1 = __expf(m1 - mn1);
      float e0  = __expf(g0 - mn0), e1  = __expf(g1 - mn1);
      l0 = fmaf(l0, cr0, e0);
      l1 = fmaf(l1, cr1, e1);
      a0 = fmaf(a0, cr0, e0 * (vj.x + de0));
      a1 = fmaf(a1, cr1, e1 * (vj.y + de1));
      m0 = mn0; m1 = mn1;
    }
    float2 o; o.x = a0 / l0; o.y = a1 / l1;
    *(float2*)(Y + (size_t)p*128 + c0) = o;
  }
}

// ---------------- decoder head: logits = relu(bn(t)) @ dec_w2 + dec_b2 ----------------
__global__ __launch_bounds__(256) void k_dec2(const float* __restrict__ T,
    const float* __restrict__ sc, const float* __restrict__ sh,
    const float* __restrict__ W, const float* __restrict__ bias, float* __restrict__ out)
{
  __shared__ float xs[64][132];   // row stride 132 floats -> 16B-aligned float4 rows
  __shared__ float wt[13][128];
  int tid = threadIdx.x;
  int pb = blockIdx.x * 64;
  for (int i = tid; i < 13 * 128; i += 256) {
    int cls = i >> 7, k = i & 127;
    wt[cls][k] = W[k*13 + cls];
  }
  for (int i = tid; i < 64 * 32; i += 256) {
    int p = i >> 5, k = (i & 31) * 4;
    float4 v = *(const float4*)(T + (size_t)(pb + p)*128 + k);
    v.x = fmaxf(fmaf(v.x, sc[k+0], sh[k+0]), 0.f);
    v.y = fmaxf(fmaf(v.y, sc[k+1], sh[k+1]), 0.f);
    v.z = fmaxf(fmaf(v.z, sc[k+2], sh[k+2]), 0.f);
    v.w = fmaxf(fmaf(v.w, sc[k+3], sh[k+3]), 0.f);
    xs[p][k+0] = v.x; xs[p][k+1] = v.y; xs[p][k+2] = v.z; xs[p][k+3] = v.w;
  }
  __syncthreads();
  for (int o = tid; o < 64 * 13; o += 256) {
    int p = o / 13, cls = o - p * 13;
    float acc = bias[cls];
    const float4* xr = (const float4*)&xs[p][0];
    const float4* wr = (const float4*)&wt[cls][0];
    #pragma unroll 8
    for (int k4 = 0; k4 < 32; ++k4) {
      float4 a = xr[k4], w = wr[k4];
      acc = fmaf(a.x, w.x, acc);
      acc = fmaf(a.y, w.y, acc);
      acc = fmaf(a.z, w.z, acc);
      acc = fmaf(a.w, w.w, acc);
    }
    out[(size_t)(pb + p)*13 + cls] = acc;
  }
}

extern "C" void kernel_launch(void* const* d_in, const int* in_sizes, int n_in,
                              void* d_out, int out_size, void* d_ws, size_t ws_size,
                              hipStream_t stream)
{
  const float* pts      = (const float*)d_in[0];
  const float* embed_w1 = (const float*)d_in[1];
  const float* embed_b1 = (const float*)d_in[2];
  const float* bn1_g    = (const float*)d_in[3];
  const float* bn1_b    = (const float*)d_in[4];
  const float* embed_w2 = (const float*)d_in[5];
  const float* embed_b2 = (const float*)d_in[6];
  const float* bne_g    = (const float*)d_in[7];
  const float* bne_b    = (const float*)d_in[8];
  const float* l0_lin   = (const float*)d_in[9];
  const float* l0_src   = (const float*)d_in[10];
  const float* l0_dst   = (const float*)d_in[11];
  const float* l0_pos_w = (const float*)d_in[12];
  const float* l0_pos_b = (const float*)d_in[13];
  const float* l0_bn_g  = (const float*)d_in[14];
  const float* l0_bn_b  = (const float*)d_in[15];
  const float* l1_lin   = (const float*)d_in[16];
  const float* l1_src   = (const float*)d_in[17];
  const float* l1_dst   = (const float*)d_in[18];
  const float* l1_pos_w = (const float*)d_in[19];
  const float* l1_pos_b = (const float*)d_in[20];
  const float* l1_bn_g  = (const float*)d_in[21];
  const float* l1_bn_b  = (const float*)d_in[22];
  const float* dec_w1   = (const float*)d_in[23];
  const float* dec_b1   = (const float*)d_in[24];
  const float* dec_bn_g = (const float*)d_in[25];
  const float* dec_bn_b = (const float*)d_in[26];
  const float* dec_w2   = (const float*)d_in[27];
  const float* dec_b2   = (const float*)d_in[28];

  char* ws = (char*)d_ws;
  const size_t MB = 1024 * 1024;
  float* h1  = (float*)(ws + 0);          // 8 MB  [P,64]
  float* h2  = (float*)(ws + 8*MB);       // 8 MB  [P,64]
  int*   idx = (int*)  (ws + 16*MB);      // 2 MB  [P,16]
  float* v0  = (float*)(ws + 18*MB);      // 16 MB [P,128]  (reused for layer1)
  float* s0  = (float*)(ws + 34*MB);      // 16 MB
  float* d0  = (float*)(ws + 50*MB);      // 16 MB
  float* y0  = (float*)(ws + 66*MB);      // 16 MB
  float* y1  = (float*)(ws + 82*MB);      // 16 MB
  float* tt  = (float*)(ws + 0);          // 16 MB overlay on h1/h2 (dead by then)
  float4* pts4 = (float4*)(ws + 18*MB);   // 512 KB overlay on v0 (dead once layer-0 proj runs)
  float* st  = (float*)(ws + 98*MB);      // 8 KB stats
  float *sum1=st+0,    *ss1=st+64,   *sc1=st+128,  *sh1=st+192;
  float *sum2=st+256,  *ss2=st+320,  *sc2=st+384,  *sh2=st+448;
  float *sum3=st+512,  *ss3=st+640,  *sc3=st+768,  *sh3=st+896;
  float *sum4=st+1024, *ss4=st+1152, *sc4=st+1280, *sh4=st+1408;
  float *sum5=st+1536, *ss5=st+1664, *sc5=st+1792, *sh5=st+1920;

  hipMemsetAsync(st, 0, 2048 * sizeof(float), stream);

  // kNN graph (runs first; pts4 overlays v0, which is only written after k_knn completes)
  k_prep<<<128, 256, 0, stream>>>(pts, pts4);
  k_knn<<<8192, 256, 0, stream>>>(pts4, idx);

  // embedding MLP
  k_embed1<<<128, 256, 0, stream>>>(pts, embed_w1, embed_b1, h1);
  k_stats<64><<<128, 256, 0, stream>>>(h1, sum1, ss1);
  k_finalize<<<1, 64, 0, stream>>>(64, sum1, ss1, bn1_g, bn1_b, sc1, sh1);
  k_proj<64,64><<<dim3(512,1), 256, 0, stream>>>(h1, sc1, sh1,
      embed_w2, embed_w2, embed_w2, embed_b2, embed_b2, embed_b2, h2, h2, h2);
  k_stats<64><<<128, 256, 0, stream>>>(h2, sum2, ss2);
  k_finalize<<<1, 64, 0, stream>>>(64, sum2, ss2, bne_g, bne_b, sc2, sh2);

  // layer 0
  k_proj<64,128><<<dim3(512,3), 256, 0, stream>>>(h2, sc2, sh2,
      l0_lin, l0_src, l0_dst, nullptr, nullptr, nullptr, v0, s0, d0);
  k_conv<<<1024, 256, 0, stream>>>(v0, s0, d0, pts, idx, l0_pos_w, l0_pos_b, y0);
  k_stats<128><<<128, 256, 0, stream>>>(y0, sum3, ss3);
  k_finalize<<<1, 128, 0, stream>>>(128, sum3, ss3, l0_bn_g, l0_bn_b, sc3, sh3);

  // layer 1
  k_proj<128,128><<<dim3(512,3), 256, 0, stream>>>(y0, sc3, sh3,
      l1_lin, l1_src, l1_dst, nullptr, nullptr, nullptr, v0, s0, d0);
  k_conv<<<1024, 256, 0, stream>>>(v0, s0, d0, pts, idx, l1_pos_w, l1_pos_b, y1);
  k_stats<128><<<128, 256, 0, stream>>>(y1, sum4, ss4);
  k_finalize<<<1, 128, 0, stream>>>(128, sum4, ss4, l1_bn_g, l1_bn_b, sc4, sh4);

  // decoder
  k_proj<128,128><<<dim3(512,1), 256, 0, stream>>>(y1, sc4, sh4,
      dec_w1, dec_w1, dec_w1, dec_b1, dec_b1, dec_b1, tt, tt, tt);
  k_stats<128><<<128, 256, 0, stream>>>(tt, sum5, ss5);
  k_finalize<<<1, 128, 0, stream>>>(128, sum5, ss5, dec_bn_g, dec_bn_b, sc5, sh5);
  k_dec2<<<512, 256, 0, stream>>>(tt, sc5, sh5, dec_w2, dec_b2, (float*)d_out);
}